// Round 7
// baseline (245.529 us; speedup 1.0000x reference)
//
#include <hip/hip_runtime.h>

#define N_ANCHORS 5000
#define N_CLASSES 80
#define OUT_COLS  (N_CLASSES + 4)   // 84
#define MAX_BOXES 300
#define SCORE_THR 0.05f

#define NWORDS    80                 // ceil(5000/64)=79, pad to 80
#define NB        4096               // score buckets per class
#define SORT_PAD  5056
#define NSCAN     80                 // scanner blocks (one per class)
#define NHELP     80                 // helper blocks (mask + box columns)
#define CPT       20                 // entries per thread (20*256=5120>=5000)

typedef unsigned long long u64;
typedef unsigned int u32;

__device__ __forceinline__ float readlane_f(float v, int l) {
    return __int_as_float(__builtin_amdgcn_readlane(__float_as_int(v), l));
}
// monotone score->bucket map (exactness never depends on it; only load balance)
__device__ __forceinline__ int bucket_of(float s) {
    float u = sqrtf(s);
    int b = (int)((u - 0.2236f) * 5275.0f);
    return min(max(b, 0), NB - 1);
}

__global__ __launch_bounds__(256, 1) void nms_all(const float* __restrict__ boxes,
                                                  const float4* __restrict__ boxes4,
                                                  const float* __restrict__ cls,
                                                  u64* __restrict__ mask,
                                                  u32* __restrict__ bar,
                                                  float* __restrict__ out) {
    // LDS carve (57760 B total; helpers overlay the front)
    __shared__ __align__(16) char SMEM[57760];
    u64* lk   = (u64*)SMEM;                    // 5056 u64 = 40448 B sorted keys
    u64* BM   = (u64*)(SMEM + 40448);          // 80 u64 suppressed bitmap
    u32* hist = (u32*)(SMEM + 41088);          // 4096 u32 bucket cursors
    u32* wtot = (u32*)(SMEM + 57472);          // 8 u32 scan temps / broadcasts
    u32* kj   = (u32*)(SMEM + 57504);          // 64 u32 kept indices per pass

    const int t = threadIdx.x;
    const int lane = t & 63;
    const int wave = t >> 6;

    if (blockIdx.x >= NSCAN) {
        // ================= helper: box columns + IoU bitmask =================
        float4* jb = (float4*)SMEM;            // 4*64*16 = 4096 B
        float*  ja = (float*)(SMEM + 4096);    // 1024 B
        const int hb = blockIdx.x - NSCAN;

        for (int i = hb * 256 + t; i < N_ANCHORS * 4; i += NHELP * 256)
            out[(i >> 2) * OUT_COLS + (i & 3)] = boxes[i];

        for (int job = hb; job < 79 * 20; job += NHELP) {
            int ic = job / 20, wq = job % 20;
            int w = wq * 4 + wave;             // word 0..79
            int j = w * 64 + lane;
            float4 v = make_float4(3e8f, 3e8f, 3e8f, 3e8f);
            float aj = 0.f;
            if (j < N_ANCHORS) { v = boxes4[j]; aj = (v.z - v.x) * (v.w - v.y); }
            jb[wave * 64 + lane] = v;          // same-wave lockstep: no barrier needed
            ja[wave * 64 + lane] = aj;
            int i = ic * 64 + lane;
            if (i < N_ANCHORS) {
                float4 bi = boxes4[i];
                float ar = (bi.z - bi.x) * (bi.w - bi.y);
                u64 bits = 0ull;
                #pragma unroll 8
                for (int q = 0; q < 64; ++q) {
                    float4 bj = jb[wave * 64 + q];
                    float iw = fmaxf(fminf(bi.z, bj.z) - fmaxf(bi.x, bj.x), 0.0f);
                    float ih = fmaxf(fminf(bi.w, bj.w) - fmaxf(bi.y, bj.y), 0.0f);
                    if (3.0f * (iw * ih) > ar + ja[wave * 64 + q]) bits |= (1ull << q); // IoU>0.5
                }
                mask[(size_t)i * NWORDS + w] = bits;
            }
        }
        __syncthreads();
        if (t == 0) __hip_atomic_fetch_add(bar, 1u, __ATOMIC_RELEASE, __HIP_MEMORY_SCOPE_AGENT);
        return;
    }

    // ================= scanner: class c =================
    const int c = blockIdx.x;

    // zero my score column (out is poisoned each call)
    for (int j = t; j < N_ANCHORS; j += 256) out[(size_t)j * OUT_COLS + 4 + c] = 0.0f;

    // ---- bucket sort (LDS-resident), overlapped with helpers ----
    u32 sb[CPT];
    #pragma unroll
    for (int m = 0; m < CPT; ++m) {
        int j = t + m * 256;
        sb[m] = 0u;
        if (j < N_ANCHORS) {
            float s = cls[(size_t)j * N_CLASSES + c];
            if (s > SCORE_THR) sb[m] = __float_as_uint(s);
        }
    }
    for (int b = t; b < NB; b += 256) hist[b] = 0u;
    if (t < NWORDS) BM[t] = 0ull;
    __syncthreads();
    #pragma unroll
    for (int m = 0; m < CPT; ++m)
        if (sb[m]) atomicAdd(&hist[bucket_of(__uint_as_float(sb[m]))], 1u);
    __syncthreads();

    const int hbase = t * 16;
    u32 vals[16]; u32 run = 0;
    #pragma unroll
    for (int k = 0; k < 16; ++k) { run += hist[hbase + k]; vals[k] = run; }
    u32 x = run;
    #pragma unroll
    for (int off = 1; off < 64; off <<= 1) { u32 y = __shfl_up(x, off); if (lane >= off) x += y; }
    if (lane == 63) wtot[wave] = x;
    __syncthreads();
    u32 woff = 0;
    for (int w2 = 0; w2 < wave; ++w2) woff += wtot[w2];
    const u32 exb = woff + x - run;
    #pragma unroll
    for (int k = 0; k < 16; ++k) hist[hbase + k] = exb + (k ? vals[k - 1] : 0u);
    __syncthreads();
    #pragma unroll
    for (int m = 0; m < CPT; ++m) {
        if (sb[m]) {
            int j = t + m * 256;
            u32 pos = atomicAdd(&hist[bucket_of(__uint_as_float(sb[m]))], 1u);
            lk[pos] = ((u64)sb[m] << 32) | (u32)(~(u32)j);   // score desc, idx asc
        }
    }
    __syncthreads();
    const int total = (int)hist[NB - 1];
    for (int b = hbase; b < hbase + 16; ++b) {      // exact sort within buckets
        int s0 = b ? (int)hist[b - 1] : 0;
        int e  = (int)hist[b];
        for (int i = s0 + 1; i < e; ++i) {
            u64 key = lk[i]; int q = i - 1;
            while (q >= s0 && lk[q] < key) { lk[q + 1] = lk[q]; --q; }
            lk[q + 1] = key;
        }
    }
    __syncthreads();

    // ---- acquire mask ----
    if (t == 0) {
        while (__hip_atomic_load(bar, __ATOMIC_ACQUIRE, __HIP_MEMORY_SCOPE_AGENT) < NHELP)
            __builtin_amdgcn_s_sleep(8);
    }
    __syncthreads();

    // ---- passes: resolve top-64 live, OR kept rows, compact survivors ----
    int nlive = total;
    int kept = 0;
    while (nlive > 0 && kept < MAX_BOXES) {
        const int m = min(nlive, 64);
        if (wave == 0) {
            u64 key = (lane < m) ? lk[lane] : 0ull;
            bool valid = (key != 0ull);
            u32 j = valid ? ~(u32)key : 0u;
            float sc = __uint_as_float((u32)(key >> 32));
            float4 bx = valid ? boxes4[j] : make_float4(0.f, 0.f, 0.f, 0.f);
            float ar = (bx.z - bx.x) * (bx.w - bx.y);
            bool alive = valid;                       // pre-filtered: all alive
            u64 rem = __ballot(alive);
            u64 km = 0ull;
            while (rem) {                             // pure-ALU keep chain
                int pos = __ffsll((long long)rem) - 1;
                km |= 1ull << pos;
                ++kept;
                if (kept == MAX_BOXES) break;
                float kx1 = readlane_f(bx.x, pos);
                float ky1 = readlane_f(bx.y, pos);
                float kx2 = readlane_f(bx.z, pos);
                float ky2 = readlane_f(bx.w, pos);
                float sAB = (kx2 - kx1) * (ky2 - ky1) + ar;
                float iw = fmaxf(fminf(kx2, bx.z) - fmaxf(kx1, bx.x), 0.0f);
                float ih = fmaxf(fminf(ky2, bx.w) - fmaxf(ky1, bx.y), 0.0f);
                alive = alive && !(3.0f * (iw * ih) > sAB);   // IoU>0.5 (kills pos)
                rem = __ballot(alive);
            }
            if ((km >> lane) & 1ull) {
                out[(size_t)j * OUT_COLS + 4 + c] = sc;
                kj[__popcll(km & ((1ull << lane) - 1ull))] = j;
            }
            if (lane == 0) { wtot[4] = (u32)kept; wtot[5] = (u32)__popcll(km); }
        }
        __syncthreads();
        kept = (int)wtot[4];
        const int nk = (int)wtot[5];
        if (t < NWORDS) {                  // 80-wide parallel row OR (one latency)
            u64 acc = 0ull;
            for (int r = 0; r < nk; ++r) acc |= mask[(size_t)kj[r] * NWORDS + t];
            BM[t] |= acc;
        }
        const int rest = nlive - m;
        if (rest <= 0 || kept >= MAX_BOXES) break;
        __syncthreads();                   // BM complete before compaction reads

        // stable compaction lk[m..m+rest) -> lk[0..newlive)
        u64 kreg[CPT]; int cnt = 0;
        #pragma unroll
        for (int i = 0; i < CPT; ++i) {
            int rel = t * CPT + i;
            if (rel < rest) {
                u64 kk = lk[m + rel];
                u32 j = ~(u32)kk;
                if (!((BM[j >> 6] >> (j & 63)) & 1ull)) kreg[cnt++] = kk;
            }
        }
        __syncthreads();                   // all reads done before overwrite
        u32 xc = (u32)cnt;
        #pragma unroll
        for (int off = 1; off < 64; off <<= 1) { u32 y = __shfl_up(xc, off); if (lane >= off) xc += y; }
        if (lane == 63) wtot[wave] = xc;
        __syncthreads();
        u32 wof = 0;
        for (int w2 = 0; w2 < wave; ++w2) wof += wtot[w2];
        u32 basec = wof + xc - (u32)cnt;
        for (int i = 0; i < cnt; ++i) lk[basec + i] = kreg[i];
        const int newlive = (int)(wtot[0] + wtot[1] + wtot[2] + wtot[3]);
        __syncthreads();                   // writes visible before next pass
        nlive = newlive;
    }
}

extern "C" void kernel_launch(void* const* d_in, const int* in_sizes, int n_in,
                              void* d_out, int out_size, void* d_ws, size_t ws_size,
                              hipStream_t stream) {
    const float* boxes = (const float*)d_in[0];
    const float* cls   = (const float*)d_in[1];
    float* out = (float*)d_out;

    u32* bar  = (u32*)d_ws;                                  // barrier counter
    u64* mask = (u64*)((char*)d_ws + 1024);                  // 3.20 MB

    hipMemsetAsync(bar, 0, 64, stream);                      // reset barrier each call
    nms_all<<<NSCAN + NHELP, 256, 0, stream>>>(boxes, (const float4*)boxes, cls,
                                               mask, bar, out);
}